// Round 3
// baseline (145.408 us; speedup 1.0000x reference)
//
#include <hip/hip_runtime.h>
#include <math.h>

#define BB 64
#define DD 512
#define HH 8
#define EPS 1e-8f

// Raw v_rcp_f32 (~1 ulp). Used identically for the softmax max (m) and the
// per-j r, so r-m cancels exactly at the argmin (same instruction, same input).
__device__ __forceinline__ float fast_rcp(float d) {
    return __builtin_amdgcn_rcpf(d);
}

__global__ __launch_bounds__(256) void flattn_kernel(
    const float* __restrict__ x,
    const float* __restrict__ alphas,
    const float* __restrict__ betas,
    float* __restrict__ out)
{
    const int b  = blockIdx.x;     // batch
    const int ic = blockIdx.y;     // i-chunk (0..1)
    const int h  = blockIdx.z;     // head

    const float a0 = alphas[h * 3 + 0];
    const float a1 = alphas[h * 3 + 1];
    const float a2 = alphas[h * 3 + 2];
    const float b0 = betas[h * 3 + 0];
    const float b1 = betas[h * 3 + 1];
    const float b2 = betas[h * 3 + 2];

    // Wave-uniform row pointer: x[j] loads in the j-loops below have uniform
    // addresses -> compiler emits s_load (scalar cache), not LDS/VMEM.
    const float* __restrict__ xrow = x + b * DD;

    const int i = ic * 256 + threadIdx.x;           // one i per thread
    const float xi = xrow[i];                        // per-lane vector load
    const float ki = fmaf(a1, xi, b1);
    const float c  = b0 - ki;                        // q_j - k_i = a0*x_j + c

    // Pass 1: min_j |a0*x_j + c|   (v_fma + v_min(abs) = 2 ops/j, SGPR-fed)
    float mind = 3.0e38f;
    #pragma unroll 16
    for (int j = 0; j < DD; ++j) {
        float t = fmaf(a0, xrow[j], c);
        mind = fminf(mind, fabsf(t));
    }
    const float m = fast_rcp(mind + EPS);           // same expr as pass 2
    const float log2e = 1.4426950408889634f;
    const float negmlog = -m * log2e;

    // Pass 2: softmax-weighted sums. No vs[] array: fold a2,b2 afterwards via
    //   sum_j s_j*(a2*x_j+b2) = a2*sxsum + b2*ssum.
    float ssum = 0.0f, sxsum = 0.0f;
    #pragma unroll 8
    for (int j = 0; j < DD; ++j) {
        float xj = xrow[j];
        float t  = fmaf(a0, xj, c);
        float d  = fabsf(t) + EPS;
        float r  = fast_rcp(d);
        float s  = __builtin_amdgcn_exp2f(fmaf(r, log2e, negmlog));
        ssum  += s;
        sxsum  = fmaf(s, xj, sxsum);
    }

    const float scale = 0.04419417382415922f;        // 1/sqrt(512)
    float svsum = fmaf(a2, sxsum, b2 * ssum);
    float att = svsum * fast_rcp(ssum) * scale;
    if (h == 0) att += xi;
    atomicAdd(&out[b * DD + i], att);
}

extern "C" void kernel_launch(void* const* d_in, const int* in_sizes, int n_in,
                              void* d_out, int out_size, void* d_ws, size_t ws_size,
                              hipStream_t stream) {
    const float* x      = (const float*)d_in[0];
    const float* alphas = (const float*)d_in[1];
    const float* betas  = (const float*)d_in[2];
    float* out = (float*)d_out;

    hipMemsetAsync(out, 0, (size_t)out_size * sizeof(float), stream);

    dim3 grid(BB, 2, HH);
    dim3 block(256);
    flattn_kernel<<<grid, block, 0, stream>>>(x, alphas, betas, out);
}

// Round 4
// 92.033 us; speedup vs baseline: 1.5799x; 1.5799x over previous
//
#include <hip/hip_runtime.h>
#include <math.h>

#define BB 64
#define DD 512
#define HH 8
#define EPS 1e-8f

// Raw v_rcp_f32 (~1 ulp). Used identically for the softmax max (m) and the
// per-j r, so r-m cancels exactly at the argmin (same instruction, same input).
__device__ __forceinline__ float fast_rcp(float d) {
    return __builtin_amdgcn_rcpf(d);
}

// Block = 512 threads: (ii, jc) = (tid & 255, tid >> 8).
// Each block handles 256 i's of one (b, h); each jc-half handles 256 j's.
// j-split doubles resident waves -> 32 waves/CU (100% of thread slots).
__global__ __launch_bounds__(512, 8) void flattn_kernel(
    const float* __restrict__ x,
    const float* __restrict__ alphas,
    const float* __restrict__ betas,
    float* __restrict__ out)
{
    const int b  = blockIdx.x;     // batch
    const int ic = blockIdx.y;     // i-chunk (0..1)
    const int h  = blockIdx.z;     // head

    __shared__ float xs[DD];
    __shared__ float mind_sh[2][256];
    __shared__ float ss_sh[256];
    __shared__ float sx_sh[256];

    const int tid = threadIdx.x;
    const int ii  = tid & 255;
    const int jc  = tid >> 8;          // wave-uniform (waves 0-3 -> 0, 4-7 -> 1)
    const int i   = ic * 256 + ii;

    const float a0 = alphas[h * 3 + 0];
    const float a1 = alphas[h * 3 + 1];
    const float a2 = alphas[h * 3 + 2];
    const float b0 = betas[h * 3 + 0];
    const float b1 = betas[h * 3 + 1];
    const float b2 = betas[h * 3 + 2];

    xs[tid] = x[b * DD + tid];
    __syncthreads();

    const float xi = xs[i];
    const float c  = b0 - fmaf(a1, xi, b1);   // q_j - k_i = a0*x_j + c

    const int j0 = jc * 256;

    // Pass 1: local min over this jc-half (fma + min(abs) = 2 VALU/j)
    float mind = 3.0e38f;
    #pragma unroll 4
    for (int j = j0; j < j0 + 256; j += 4) {
        float4 x4 = *(const float4*)&xs[j];    // ds_read_b128 broadcast
        mind = fminf(mind, fabsf(fmaf(a0, x4.x, c)));
        mind = fminf(mind, fabsf(fmaf(a0, x4.y, c)));
        mind = fminf(mind, fabsf(fmaf(a0, x4.z, c)));
        mind = fminf(mind, fabsf(fmaf(a0, x4.w, c)));
    }
    mind_sh[jc][ii] = mind;
    __syncthreads();

    // Global min -> shared m for both halves (no rescale factors needed).
    mind = fminf(mind_sh[0][ii], mind_sh[1][ii]);
    const float m = fast_rcp(mind + EPS);      // same expr as pass 2's r
    const float log2e = 1.4426950408889634f;
    const float negml = -m * log2e;

    // Pass 2: softmax-weighted sums over this jc-half.
    //   sum_j s_j*(a2*x_j+b2) = a2*sx + b2*ss  (vs[] folded out)
    float ss = 0.0f, sx = 0.0f;
    #pragma unroll 2
    for (int j = j0; j < j0 + 256; j += 4) {
        float4 x4 = *(const float4*)&xs[j];
        {
            float t = fmaf(a0, x4.x, c);
            float r = fast_rcp(fabsf(t) + EPS);
            float s = __builtin_amdgcn_exp2f(fmaf(r, log2e, negml));
            ss += s; sx = fmaf(s, x4.x, sx);
        }
        {
            float t = fmaf(a0, x4.y, c);
            float r = fast_rcp(fabsf(t) + EPS);
            float s = __builtin_amdgcn_exp2f(fmaf(r, log2e, negml));
            ss += s; sx = fmaf(s, x4.y, sx);
        }
        {
            float t = fmaf(a0, x4.z, c);
            float r = fast_rcp(fabsf(t) + EPS);
            float s = __builtin_amdgcn_exp2f(fmaf(r, log2e, negml));
            ss += s; sx = fmaf(s, x4.z, sx);
        }
        {
            float t = fmaf(a0, x4.w, c);
            float r = fast_rcp(fabsf(t) + EPS);
            float s = __builtin_amdgcn_exp2f(fmaf(r, log2e, negml));
            ss += s; sx = fmaf(s, x4.w, sx);
        }
    }

    // Merge the two jc-halves via LDS, then one atomic per (i, h).
    if (jc == 1) { ss_sh[ii] = ss; sx_sh[ii] = sx; }
    __syncthreads();
    if (jc == 0) {
        ss += ss_sh[ii];
        sx += sx_sh[ii];
        const float scale = 0.04419417382415922f;   // 1/sqrt(512)
        float sv  = fmaf(a2, sx, b2 * ss);
        float att = sv * fast_rcp(ss) * scale;
        if (h == 0) att += xi;
        atomicAdd(&out[b * DD + i], att);
    }
}

extern "C" void kernel_launch(void* const* d_in, const int* in_sizes, int n_in,
                              void* d_out, int out_size, void* d_ws, size_t ws_size,
                              hipStream_t stream) {
    const float* x      = (const float*)d_in[0];
    const float* alphas = (const float*)d_in[1];
    const float* betas  = (const float*)d_in[2];
    float* out = (float*)d_out;

    hipMemsetAsync(out, 0, (size_t)out_size * sizeof(float), stream);

    dim3 grid(BB, 2, HH);
    dim3 block(512);
    flattn_kernel<<<grid, block, 0, stream>>>(x, alphas, betas, out);
}